// Round 5
// baseline (108.203 us; speedup 1.0000x reference)
//
#include <hip/hip_runtime.h>
#include <hip/hip_bf16.h>

#define N_B   4
#define T_LEN 1024
#define NREF  128
#define H     4
#define KQ    128
#define LD    128
#define HKQ   512
#define HLD   512

typedef __attribute__((ext_vector_type(8))) short bf16x8;   // 8 bf16 = 4 VGPRs
typedef __attribute__((ext_vector_type(4))) float f32x4;

union V8 { __hip_bfloat16 h[8]; bf16x8 v; };

__device__ __forceinline__ void sincos_pair(float t, int i, float* s, float* c) {
    // freq i in [0,32): angle = 48*t*exp(-2i*ln(10)/64)
    float div = __expf(-(float)(2 * i) * (2.302585093f / 64.0f));
    __sincosf(48.0f * t * div, s, c);
}

// pack_kernel: job-dispatched producer kernel.
//  jobs 0..7    : A-tensor  (h = j>>1, q-half = j&1): hq = qin@Wq_h + bq (MFMA),
//                 then A_h = hq @ Wk_h^T (MFMA, B from global fp32->bf16)
//  jobs 8..71   : k_in build (64 rows each) bf16 [4096][128]
//  jobs 72..135 : xT transpose x[b,t,v] f32 -> xT[b,v,t] bf16
//  jobs 136..143: WoT transpose Wo[512][128] f32 -> WoT[128][512] bf16 (64 i-rows each)
__global__ __launch_bounds__(256) void pack_kernel(
    const float* __restrict__ ts, const int* __restrict__ ys0, const int* __restrict__ ys1,
    const float* __restrict__ x,
    const float* __restrict__ emb0, const float* __restrict__ emb1,
    const float* __restrict__ Wq, const float* __restrict__ bq,
    const float* __restrict__ Wk, const float* __restrict__ Wo,
    __hip_bfloat16* __restrict__ A, __hip_bfloat16* __restrict__ kin,
    __hip_bfloat16* __restrict__ xT, __hip_bfloat16* __restrict__ WoT)
{
    __shared__ __align__(16) unsigned char smem[49152];
    int job = blockIdx.x;
    int tid = threadIdx.x;

    if (job < 8) {
        // ---------------- A job ----------------
        __hip_bfloat16* buf0 = (__hip_bfloat16*)smem;            // 64*128 bf16 = 16 KB (qin -> hq)
        __hip_bfloat16* wqt  = (__hip_bfloat16*)(smem + 16384);  // 128*128 bf16 = 32 KB (WqT)
        int h = job >> 1, qbase = (job & 1) * 64;

        // build qin (64 q rows x 128) bf16, XOR-swizzled rows
        for (int u = 0; u < 4; ++u) {
            int slot = u * 256 + tid;      // 0..1023
            int q = slot >> 4;             // local row 0..63
            int c0 = (slot & 15) * 8;
            V8 v;
            if (c0 < 64) {
                float t = (float)(qbase + q) / 127.0f;   // linspace(0,1,128)
                #pragma unroll
                for (int jj = 0; jj < 8; jj += 2) {
                    float s, c;
                    sincos_pair(t, (c0 + jj) >> 1, &s, &c);
                    v.h[jj] = __float2bfloat16(s);
                    v.h[jj + 1] = __float2bfloat16(c);
                }
            } else if (c0 < 96) {
                #pragma unroll
                for (int jj = 0; jj < 8; ++jj) v.h[jj] = __float2bfloat16(emb0[100 * 32 + (c0 - 64) + jj]);
            } else {
                #pragma unroll
                for (int jj = 0; jj < 8; ++jj) v.h[jj] = __float2bfloat16(emb1[50 * 32 + (c0 - 96) + jj]);
            }
            int idx = (q * 128 + c0) ^ ((q & 7) << 3);
            *(bf16x8*)&buf0[idx] = v.v;
        }
        // build WqT[d][i] bf16, swizzled (transpose of Wq_h)
        for (int u = 0; u < 16; ++u) {
            int s = u * 256 + tid;         // 0..4095
            int i = s >> 5;                // 0..127
            int d0 = (s & 31) * 4;
            float4 w = *(const float4*)&Wq[(size_t)i * HKQ + h * KQ + d0];
            float wv[4] = {w.x, w.y, w.z, w.w};
            #pragma unroll
            for (int jj = 0; jj < 4; ++jj) {
                int d = d0 + jj;
                wqt[(d * 128 + i) ^ ((d & 7) << 3)] = __float2bfloat16(wv[jj]);
            }
        }
        __syncthreads();

        int wave = tid >> 6, lane = tid & 63, lm = lane & 15, lg = lane >> 4;
        // stage 1: hq[64q x 128d] = qin @ WqT + bq; wave owns 16 q rows
        f32x4 acc[8];
        #pragma unroll
        for (int dt = 0; dt < 8; ++dt) acc[dt] = f32x4{0.f, 0.f, 0.f, 0.f};
        #pragma unroll
        for (int ks = 0; ks < 4; ++ks) {
            int q = wave * 16 + lm;
            bf16x8 af = *(bf16x8*)&buf0[(q * 128 + ks * 32 + 8 * lg) ^ ((q & 7) << 3)];
            #pragma unroll
            for (int dt = 0; dt < 8; ++dt) {
                int d = dt * 16 + lm;
                bf16x8 bfr = *(bf16x8*)&wqt[(d * 128 + ks * 32 + 8 * lg) ^ ((d & 7) << 3)];
                acc[dt] = __builtin_amdgcn_mfma_f32_16x16x32_bf16(af, bfr, acc[dt], 0, 0, 0);
            }
        }
        __syncthreads();   // qin fully consumed
        // hq (+bias) -> buf0, swizzled
        #pragma unroll
        for (int dt = 0; dt < 8; ++dt) {
            int d = dt * 16 + lm;
            float bb = bq[h * KQ + d];
            #pragma unroll
            for (int r = 0; r < 4; ++r) {
                int q = wave * 16 + 4 * lg + r;
                buf0[(q * 128 + d) ^ ((q & 7) << 3)] = __float2bfloat16(acc[dt][r] + bb);
            }
        }
        __syncthreads();
        // stage 2: A[64q x 128i] = hq @ Wk_h^T (contract d); B rows from global fp32
        f32x4 acc2[8];
        #pragma unroll
        for (int it = 0; it < 8; ++it) acc2[it] = f32x4{0.f, 0.f, 0.f, 0.f};
        #pragma unroll
        for (int ks = 0; ks < 4; ++ks) {
            int q = wave * 16 + lm;
            bf16x8 af = *(bf16x8*)&buf0[(q * 128 + ks * 32 + 8 * lg) ^ ((q & 7) << 3)];
            #pragma unroll
            for (int it = 0; it < 8; ++it) {
                int i2 = it * 16 + lm;
                const float* wkp = &Wk[(size_t)i2 * HKQ + h * KQ + ks * 32 + 8 * lg];
                float4 wa = *(const float4*)wkp;
                float4 wb = *(const float4*)(wkp + 4);
                V8 bv;
                bv.h[0] = __float2bfloat16(wa.x); bv.h[1] = __float2bfloat16(wa.y);
                bv.h[2] = __float2bfloat16(wa.z); bv.h[3] = __float2bfloat16(wa.w);
                bv.h[4] = __float2bfloat16(wb.x); bv.h[5] = __float2bfloat16(wb.y);
                bv.h[6] = __float2bfloat16(wb.z); bv.h[7] = __float2bfloat16(wb.w);
                acc2[it] = __builtin_amdgcn_mfma_f32_16x16x32_bf16(af, bv.v, acc2[it], 0, 0, 0);
            }
        }
        // store A: [h][q][i] bf16 (plain row-major)
        #pragma unroll
        for (int it = 0; it < 8; ++it) {
            int i2 = it * 16 + lm;
            #pragma unroll
            for (int r = 0; r < 4; ++r) {
                int q = qbase + wave * 16 + 4 * lg + r;
                A[((size_t)h * NREF + q) * KQ + i2] = __float2bfloat16(acc2[it][r]);
            }
        }
    } else if (job < 72) {
        // ---------------- k_in job ----------------
        int row0 = (job - 8) * 64;
        for (int u = 0; u < 4; ++u) {
            int slot = u * 256 + tid;     // 0..1023
            int r = slot >> 4;            // 0..63
            int c0 = (slot & 15) * 8;
            int bt = row0 + r;
            V8 v;
            if (c0 < 64) {
                float t = ts[bt];
                #pragma unroll
                for (int jj = 0; jj < 8; jj += 2) {
                    float s, c;
                    sincos_pair(t, (c0 + jj) >> 1, &s, &c);
                    v.h[jj] = __float2bfloat16(s);
                    v.h[jj + 1] = __float2bfloat16(c);
                }
            } else if (c0 < 96) {
                int y = ys0[bt];
                #pragma unroll
                for (int jj = 0; jj < 8; ++jj) v.h[jj] = __float2bfloat16(emb0[y * 32 + (c0 - 64) + jj]);
            } else {
                int y = ys1[bt];
                #pragma unroll
                for (int jj = 0; jj < 8; ++jj) v.h[jj] = __float2bfloat16(emb1[y * 32 + (c0 - 96) + jj]);
            }
            *(bf16x8*)&kin[(size_t)bt * KQ + c0] = v.v;
        }
    } else if (job < 136) {
        // ---------------- xT job ----------------
        __hip_bfloat16 (*tile)[136] = (__hip_bfloat16(*)[136])smem;   // 64*136*2 = 17.4 KB
        int jb = job - 72;
        int b = jb >> 4, t0 = (jb & 15) * 64;
        for (int e = tid; e < 64 * 32; e += 256) {
            int tt = e >> 5, v4 = e & 31;
            float4 xv = *(const float4*)&x[((size_t)(b * T_LEN + t0 + tt)) * LD + v4 * 4];
            tile[tt][v4 * 4 + 0] = __float2bfloat16(xv.x);
            tile[tt][v4 * 4 + 1] = __float2bfloat16(xv.y);
            tile[tt][v4 * 4 + 2] = __float2bfloat16(xv.z);
            tile[tt][v4 * 4 + 3] = __float2bfloat16(xv.w);
        }
        __syncthreads();
        int v = tid >> 1, th = (tid & 1) * 32;
        for (int i = 0; i < 32; i += 4) {
            ushort4 u;
            u.x = *(unsigned short*)&tile[th + i + 0][v];
            u.y = *(unsigned short*)&tile[th + i + 1][v];
            u.z = *(unsigned short*)&tile[th + i + 2][v];
            u.w = *(unsigned short*)&tile[th + i + 3][v];
            *(ushort4*)&xT[((size_t)b * LD + v) * T_LEN + t0 + th + i] = u;
        }
    } else {
        // ---------------- WoT job: Wo[i][j] f32 -> WoT[j][i] bf16, 64-row i slab ----------------
        __hip_bfloat16 (*tile)[130] = (__hip_bfloat16(*)[130])smem;   // 64*130*2 = 16.6 KB
        int i0 = (job - 136) * 64;
        for (int u = 0; u < 32; ++u) {
            int e = u * 256 + tid;            // 0..8191
            int il = e >> 7, j = e & 127;
            tile[il][j] = __float2bfloat16(Wo[(size_t)(i0 + il) * LD + j]);
        }
        __syncthreads();
        for (int u = 0; u < 32; ++u) {
            int s = u * 256 + tid;            // 0..8191
            int j = s >> 6, il = s & 63;
            WoT[(size_t)j * HLD + i0 + il] = tile[il][j];
        }
    }
}

// Fused attention + output projection.
// grid (8 qt, 4 b), block 256 = 4 waves; wave = head.
// Per wave: online-softmax flash over 8 chunks of 128 keys (scores A_h.kin, MFMA),
// P in wave-private swizzled LDS, PV MFMA vs xT; then barrier, att(16x512 bf16 LDS)
// @ WoT + bo via MFMA -> out.
__global__ __launch_bounds__(256) void fused_attn(const __hip_bfloat16* __restrict__ A,
                                                  const __hip_bfloat16* __restrict__ kin,
                                                  const __hip_bfloat16* __restrict__ xT,
                                                  const __hip_bfloat16* __restrict__ WoT,
                                                  const float* __restrict__ bo,
                                                  float* __restrict__ out) {
    __shared__ __hip_bfloat16 P_lds[H][16 * 128];   // per-head, XOR-swizzled rows
    __shared__ __hip_bfloat16 att_lds[16 * 512];    // XOR-swizzled rows

    int tid = threadIdx.x;
    int h = tid >> 6, lane = tid & 63;
    int lm = lane & 15, lg = lane >> 4;
    int q0 = blockIdx.x * 16, b = blockIdx.y;
    const float scale = 0.08838834764831845f;  // 1/sqrt(128)

    // A-frags for this head's 16 q rows (resident all kernel)
    bf16x8 af[4];
    #pragma unroll
    for (int ks = 0; ks < 4; ++ks)
        af[ks] = *(const bf16x8*)(A + ((size_t)h * NREF + q0 + lm) * KQ + ks * 32 + lg * 8);

    f32x4 oacc[8];
    #pragma unroll
    for (int nt = 0; nt < 8; ++nt) oacc[nt] = f32x4{0.f, 0.f, 0.f, 0.f};
    float m_[4] = {-1e30f, -1e30f, -1e30f, -1e30f};
    float l_[4] = {0.f, 0.f, 0.f, 0.f};

    for (int c = 0; c < 8; ++c) {
        int t0 = c * 128;
        // ---- scores for 128-key chunk: D[q=4lg+r][key=kt*16+lm]
        f32x4 sacc[8];
        #pragma unroll
        for (int kt = 0; kt < 8; ++kt) sacc[kt] = f32x4{0.f, 0.f, 0.f, 0.f};
        #pragma unroll
        for (int ks = 0; ks < 4; ++ks) {
            #pragma unroll
            for (int kt = 0; kt < 8; ++kt) {
                bf16x8 bfr = *(const bf16x8*)(kin + (size_t)(b * T_LEN + t0 + kt * 16 + lm) * KQ + ks * 32 + lg * 8);
                sacc[kt] = __builtin_amdgcn_mfma_f32_16x16x32_bf16(af[ks], bfr, sacc[kt], 0, 0, 0);
            }
        }
        // ---- online softmax update (rows fully within this wave's 16-lane groups)
        #pragma unroll
        for (int r = 0; r < 4; ++r) {
            int q = 4 * lg + r;
            float cm = sacc[0][r];
            #pragma unroll
            for (int kt = 1; kt < 8; ++kt) cm = fmaxf(cm, sacc[kt][r]);
            #pragma unroll
            for (int o = 8; o >= 1; o >>= 1) cm = fmaxf(cm, __shfl_xor(cm, o));
            float nm = fmaxf(m_[r], cm * scale);
            float f = __expf(m_[r] - nm);
            m_[r] = nm;
            float sum = 0.f;
            #pragma unroll
            for (int kt = 0; kt < 8; ++kt) {
                float p = __expf(sacc[kt][r] * scale - nm);
                sum += p;
                int col = kt * 16 + lm;
                P_lds[h][(q * 128 + col) ^ ((q & 7) << 3)] = __float2bfloat16(p);
            }
            #pragma unroll
            for (int o = 8; o >= 1; o >>= 1) sum += __shfl_xor(sum, o);
            l_[r] = l_[r] * f + sum;
            #pragma unroll
            for (int nt = 0; nt < 8; ++nt) oacc[nt][r] *= f;
        }
        // ---- PV accumulate: D[q][v] += P[q][k] * xT[v][k]   (wave-private P, no barrier)
        #pragma unroll
        for (int ks2 = 0; ks2 < 4; ++ks2) {
            bf16x8 pa = *(bf16x8*)&P_lds[h][(lm * 128 + ks2 * 32 + 8 * lg) ^ ((lm & 7) << 3)];
            #pragma unroll
            for (int nt = 0; nt < 8; ++nt) {
                bf16x8 xb = *(const bf16x8*)(xT + (size_t)(b * LD + nt * 16 + lm) * T_LEN + t0 + ks2 * 32 + lg * 8);
                oacc[nt] = __builtin_amdgcn_mfma_f32_16x16x32_bf16(pa, xb, oacc[nt], 0, 0, 0);
            }
        }
    }

    // ---- normalize, att -> LDS (bf16, swizzled): att[q][h*128 + nt*16+lm]
    float inv[4];
    #pragma unroll
    for (int r = 0; r < 4; ++r) inv[r] = 1.0f / l_[r];
    #pragma unroll
    for (int nt = 0; nt < 8; ++nt) {
        #pragma unroll
        for (int r = 0; r < 4; ++r) {
            int q = 4 * lg + r;
            int col = h * 128 + nt * 16 + lm;
            att_lds[(q * 512 + col) ^ ((q & 7) << 3)] = __float2bfloat16(oacc[nt][r] * inv[r]);
        }
    }
    __syncthreads();

    // ---- output projection: out[q][j] = att[q][:] @ WoT[j][:] + bo[j]; wave owns 32 j cols
    f32x4 cacc[2];
    cacc[0] = f32x4{0.f, 0.f, 0.f, 0.f};
    cacc[1] = f32x4{0.f, 0.f, 0.f, 0.f};
    #pragma unroll
    for (int ks = 0; ks < 16; ++ks) {
        bf16x8 aa = *(bf16x8*)&att_lds[(lm * 512 + ks * 32 + 8 * lg) ^ ((lm & 7) << 3)];
        #pragma unroll
        for (int nt2 = 0; nt2 < 2; ++nt2) {
            int j = h * 32 + nt2 * 16 + lm;
            bf16x8 wb = *(const bf16x8*)(WoT + (size_t)j * HLD + ks * 32 + lg * 8);
            cacc[nt2] = __builtin_amdgcn_mfma_f32_16x16x32_bf16(aa, wb, cacc[nt2], 0, 0, 0);
        }
    }
    #pragma unroll
    for (int nt2 = 0; nt2 < 2; ++nt2) {
        int j = h * 32 + nt2 * 16 + lm;
        float bb = bo[j];
        #pragma unroll
        for (int r = 0; r < 4; ++r) {
            int q = q0 + 4 * lg + r;
            out[((size_t)b * NREF + q) * LD + j] = cacc[nt2][r] + bb;
        }
    }
}

extern "C" void kernel_launch(void* const* d_in, const int* in_sizes, int n_in,
                              void* d_out, int out_size, void* d_ws, size_t ws_size,
                              hipStream_t stream) {
    const float* ts   = (const float*)d_in[0];
    const int*   ys0  = (const int*)d_in[1];
    const int*   ys1  = (const int*)d_in[2];
    const float* x    = (const float*)d_in[3];
    const float* emb0 = (const float*)d_in[4];
    const float* emb1 = (const float*)d_in[5];
    const float* Wq   = (const float*)d_in[6];
    const float* bq   = (const float*)d_in[7];
    const float* Wk   = (const float*)d_in[8];
    // d_in[9] = bk: cancels exactly in softmax (constant per (h,q) row) — unused
    const float* Wo   = (const float*)d_in[10];
    const float* bo   = (const float*)d_in[11];
    float* out = (float*)d_out;

    __hip_bfloat16* bfws = (__hip_bfloat16*)d_ws;
    __hip_bfloat16* A   = bfws;                 // 4*128*128      = 65536
    __hip_bfloat16* kin = A + 65536;            // 4096*128       = 524288
    __hip_bfloat16* xT  = kin + 524288;         // 4*128*1024     = 524288
    __hip_bfloat16* WoT = xT + 524288;          // 128*512        = 65536
    // total 1,179,648 bf16 = 2.25 MB

    hipLaunchKernelGGL(pack_kernel, dim3(144), dim3(256), 0, stream,
                       ts, ys0, ys1, x, emb0, emb1, Wq, bq, Wk, Wo, A, kin, xT, WoT);
    hipLaunchKernelGGL(fused_attn, dim3(8, 4), dim3(256), 0, stream, A, kin, xT, WoT, bo, out);
}

// Round 6
// 51.757 us; speedup vs baseline: 2.0906x; 2.0906x over previous
//
#include <hip/hip_runtime.h>
#include <hip/hip_bf16.h>

#define N_B   4
#define T_LEN 1024
#define NREF  128
#define H     4
#define KQ    128
#define LD    128
#define HKQ   512
#define HLD   512

typedef __attribute__((ext_vector_type(8))) short bf16x8;   // 8 bf16 = 4 VGPRs
typedef __attribute__((ext_vector_type(4))) float f32x4;

union V8 { __hip_bfloat16 h[8]; bf16x8 v; };

__device__ __forceinline__ void sincos_pair(float t, int i, float* s, float* c) {
    // freq i in [0,32): angle = 48*t*exp(-2i*ln(10)/64)
    float div = __expf(-(float)(2 * i) * (2.302585093f / 64.0f));
    __sincosf(48.0f * t * div, s, c);
}

// pack_kernel: job-dispatched producer kernel.
//  jobs 0..7    : A-tensor  (h = j>>1, q-half = j&1): hq = qin@Wq_h + bq (MFMA),
//                 then A_h = hq @ Wk_h^T (MFMA, B from global fp32->bf16)
//  jobs 8..71   : k_in build (64 rows each) bf16 [4096][128]
//  jobs 72..135 : xT transpose x[b,t,v] f32 -> xT[b,v,t] bf16
//  jobs 136..143: WoT transpose Wo[512][128] f32 -> WoT[128][512] bf16 (64 i-rows each)
__global__ __launch_bounds__(256) void pack_kernel(
    const float* __restrict__ ts, const int* __restrict__ ys0, const int* __restrict__ ys1,
    const float* __restrict__ x,
    const float* __restrict__ emb0, const float* __restrict__ emb1,
    const float* __restrict__ Wq, const float* __restrict__ bq,
    const float* __restrict__ Wk, const float* __restrict__ Wo,
    __hip_bfloat16* __restrict__ A, __hip_bfloat16* __restrict__ kin,
    __hip_bfloat16* __restrict__ xT, __hip_bfloat16* __restrict__ WoT)
{
    __shared__ __align__(16) unsigned char smem[49152];
    int job = blockIdx.x;
    int tid = threadIdx.x;

    if (job < 8) {
        // ---------------- A job ----------------
        __hip_bfloat16* buf0 = (__hip_bfloat16*)smem;            // 64*128 bf16 = 16 KB (qin -> hq)
        __hip_bfloat16* wqt  = (__hip_bfloat16*)(smem + 16384);  // 128*128 bf16 = 32 KB (WqT)
        int h = job >> 1, qbase = (job & 1) * 64;

        // build qin (64 q rows x 128) bf16, XOR-swizzled rows
        for (int u = 0; u < 4; ++u) {
            int slot = u * 256 + tid;      // 0..1023
            int q = slot >> 4;             // local row 0..63
            int c0 = (slot & 15) * 8;
            V8 v;
            if (c0 < 64) {
                float t = (float)(qbase + q) / 127.0f;   // linspace(0,1,128)
                #pragma unroll
                for (int jj = 0; jj < 8; jj += 2) {
                    float s, c;
                    sincos_pair(t, (c0 + jj) >> 1, &s, &c);
                    v.h[jj] = __float2bfloat16(s);
                    v.h[jj + 1] = __float2bfloat16(c);
                }
            } else if (c0 < 96) {
                #pragma unroll
                for (int jj = 0; jj < 8; ++jj) v.h[jj] = __float2bfloat16(emb0[100 * 32 + (c0 - 64) + jj]);
            } else {
                #pragma unroll
                for (int jj = 0; jj < 8; ++jj) v.h[jj] = __float2bfloat16(emb1[50 * 32 + (c0 - 96) + jj]);
            }
            int idx = (q * 128 + c0) ^ ((q & 7) << 3);
            *(bf16x8*)&buf0[idx] = v.v;
        }
        // build WqT[d][i] bf16, swizzled (transpose of Wq_h)
        for (int u = 0; u < 16; ++u) {
            int s = u * 256 + tid;         // 0..4095
            int i = s >> 5;                // 0..127
            int d0 = (s & 31) * 4;
            float4 w = *(const float4*)&Wq[(size_t)i * HKQ + h * KQ + d0];
            float wv[4] = {w.x, w.y, w.z, w.w};
            #pragma unroll
            for (int jj = 0; jj < 4; ++jj) {
                int d = d0 + jj;
                wqt[(d * 128 + i) ^ ((d & 7) << 3)] = __float2bfloat16(wv[jj]);
            }
        }
        __syncthreads();

        int wave = tid >> 6, lane = tid & 63, lm = lane & 15, lg = lane >> 4;
        // stage 1: hq[64q x 128d] = qin @ WqT + bq; wave owns 16 q rows
        f32x4 acc[8];
        #pragma unroll
        for (int dt = 0; dt < 8; ++dt) acc[dt] = f32x4{0.f, 0.f, 0.f, 0.f};
        #pragma unroll
        for (int ks = 0; ks < 4; ++ks) {
            int q = wave * 16 + lm;
            bf16x8 af = *(bf16x8*)&buf0[(q * 128 + ks * 32 + 8 * lg) ^ ((q & 7) << 3)];
            #pragma unroll
            for (int dt = 0; dt < 8; ++dt) {
                int d = dt * 16 + lm;
                bf16x8 bfr = *(bf16x8*)&wqt[(d * 128 + ks * 32 + 8 * lg) ^ ((d & 7) << 3)];
                acc[dt] = __builtin_amdgcn_mfma_f32_16x16x32_bf16(af, bfr, acc[dt], 0, 0, 0);
            }
        }
        __syncthreads();   // qin fully consumed
        // hq (+bias) -> buf0, swizzled
        #pragma unroll
        for (int dt = 0; dt < 8; ++dt) {
            int d = dt * 16 + lm;
            float bb = bq[h * KQ + d];
            #pragma unroll
            for (int r = 0; r < 4; ++r) {
                int q = wave * 16 + 4 * lg + r;
                buf0[(q * 128 + d) ^ ((q & 7) << 3)] = __float2bfloat16(acc[dt][r] + bb);
            }
        }
        __syncthreads();
        // stage 2: A[64q x 128i] = hq @ Wk_h^T (contract d); B rows from global fp32
        f32x4 acc2[8];
        #pragma unroll
        for (int it = 0; it < 8; ++it) acc2[it] = f32x4{0.f, 0.f, 0.f, 0.f};
        #pragma unroll
        for (int ks = 0; ks < 4; ++ks) {
            int q = wave * 16 + lm;
            bf16x8 af = *(bf16x8*)&buf0[(q * 128 + ks * 32 + 8 * lg) ^ ((q & 7) << 3)];
            #pragma unroll
            for (int it = 0; it < 8; ++it) {
                int i2 = it * 16 + lm;
                const float* wkp = &Wk[(size_t)i2 * HKQ + h * KQ + ks * 32 + 8 * lg];
                float4 wa = *(const float4*)wkp;
                float4 wb = *(const float4*)(wkp + 4);
                V8 bv;
                bv.h[0] = __float2bfloat16(wa.x); bv.h[1] = __float2bfloat16(wa.y);
                bv.h[2] = __float2bfloat16(wa.z); bv.h[3] = __float2bfloat16(wa.w);
                bv.h[4] = __float2bfloat16(wb.x); bv.h[5] = __float2bfloat16(wb.y);
                bv.h[6] = __float2bfloat16(wb.z); bv.h[7] = __float2bfloat16(wb.w);
                acc2[it] = __builtin_amdgcn_mfma_f32_16x16x32_bf16(af, bv.v, acc2[it], 0, 0, 0);
            }
        }
        // store A: [h][q][i] bf16 (plain row-major)
        #pragma unroll
        for (int it = 0; it < 8; ++it) {
            int i2 = it * 16 + lm;
            #pragma unroll
            for (int r = 0; r < 4; ++r) {
                int q = qbase + wave * 16 + 4 * lg + r;
                A[((size_t)h * NREF + q) * KQ + i2] = __float2bfloat16(acc2[it][r]);
            }
        }
    } else if (job < 72) {
        // ---------------- k_in job ----------------
        int row0 = (job - 8) * 64;
        for (int u = 0; u < 4; ++u) {
            int slot = u * 256 + tid;     // 0..1023
            int r = slot >> 4;            // 0..63
            int c0 = (slot & 15) * 8;
            int bt = row0 + r;
            V8 v;
            if (c0 < 64) {
                float t = ts[bt];
                #pragma unroll
                for (int jj = 0; jj < 8; jj += 2) {
                    float s, c;
                    sincos_pair(t, (c0 + jj) >> 1, &s, &c);
                    v.h[jj] = __float2bfloat16(s);
                    v.h[jj + 1] = __float2bfloat16(c);
                }
            } else if (c0 < 96) {
                int y = ys0[bt];
                #pragma unroll
                for (int jj = 0; jj < 8; ++jj) v.h[jj] = __float2bfloat16(emb0[y * 32 + (c0 - 64) + jj]);
            } else {
                int y = ys1[bt];
                #pragma unroll
                for (int jj = 0; jj < 8; ++jj) v.h[jj] = __float2bfloat16(emb1[y * 32 + (c0 - 96) + jj]);
            }
            *(bf16x8*)&kin[(size_t)bt * KQ + c0] = v.v;
        }
    } else if (job < 136) {
        // ---------------- xT job ----------------
        __hip_bfloat16 (*tile)[136] = (__hip_bfloat16(*)[136])smem;   // 64*136*2 = 17.4 KB
        int jb = job - 72;
        int b = jb >> 4, t0 = (jb & 15) * 64;
        for (int e = tid; e < 64 * 32; e += 256) {
            int tt = e >> 5, v4 = e & 31;
            float4 xv = *(const float4*)&x[((size_t)(b * T_LEN + t0 + tt)) * LD + v4 * 4];
            tile[tt][v4 * 4 + 0] = __float2bfloat16(xv.x);
            tile[tt][v4 * 4 + 1] = __float2bfloat16(xv.y);
            tile[tt][v4 * 4 + 2] = __float2bfloat16(xv.z);
            tile[tt][v4 * 4 + 3] = __float2bfloat16(xv.w);
        }
        __syncthreads();
        int v = tid >> 1, th = (tid & 1) * 32;
        for (int i = 0; i < 32; i += 4) {
            ushort4 u;
            u.x = *(unsigned short*)&tile[th + i + 0][v];
            u.y = *(unsigned short*)&tile[th + i + 1][v];
            u.z = *(unsigned short*)&tile[th + i + 2][v];
            u.w = *(unsigned short*)&tile[th + i + 3][v];
            *(ushort4*)&xT[((size_t)b * LD + v) * T_LEN + t0 + th + i] = u;
        }
    } else {
        // ---------------- WoT job: Wo[i][j] f32 -> WoT[j][i] bf16, 64-row i slab ----------------
        __hip_bfloat16 (*tile)[130] = (__hip_bfloat16(*)[130])smem;   // 64*130*2 = 16.6 KB
        int i0 = (job - 136) * 64;
        for (int u = 0; u < 32; ++u) {
            int e = u * 256 + tid;            // 0..8191
            int il = e >> 7, j = e & 127;
            tile[il][j] = __float2bfloat16(Wo[(size_t)(i0 + il) * LD + j]);
        }
        __syncthreads();
        for (int u = 0; u < 32; ++u) {
            int s = u * 256 + tid;            // 0..8191
            int j = s >> 6, il = s & 63;
            WoT[(size_t)j * HLD + i0 + il] = tile[il][j];
        }
    }
}

// Full-T online-softmax attention for one (16q, h, b): 8 waves, 4 chunks of 256 keys.
// Per chunk: wave scores its 32 keys (8 MFMA), cross-wave max via LDS, exp -> shared
// swizzled P_lds + sums, PV over all 256 keys for wave's 16 v-cols (8 MFMA), online
// rescale of O. Writes normalized att bf16 [b][q][h*128+v].
// grid (8 qt, 4 h, 4 b), block 512.
__global__ __launch_bounds__(512) void attn_kernel(const __hip_bfloat16* __restrict__ A,
                                                   const __hip_bfloat16* __restrict__ kin,
                                                   const __hip_bfloat16* __restrict__ xT,
                                                   __hip_bfloat16* __restrict__ att) {
    __shared__ __hip_bfloat16 P_lds[16 * 256];   // XOR-swizzled rows
    __shared__ float redm[8][16], reds[8][16];

    int tid = threadIdx.x;
    int w = tid >> 6, lane = tid & 63;
    int lm = lane & 15, lg = lane >> 4;
    int q0 = blockIdx.x * 16, h = blockIdx.y, b = blockIdx.z;
    const float scale = 0.08838834764831845f;  // 1/sqrt(128)

    // A-frags for the 16 q rows (resident)
    bf16x8 af[4];
    #pragma unroll
    for (int ks = 0; ks < 4; ++ks)
        af[ks] = *(const bf16x8*)(A + ((size_t)h * NREF + q0 + lm) * KQ + ks * 32 + lg * 8);

    f32x4 oacc = f32x4{0.f, 0.f, 0.f, 0.f};     // D[q=4lg+r][v = w*16+lm]
    float m_[4] = {-1e30f, -1e30f, -1e30f, -1e30f};
    float l_[4] = {0.f, 0.f, 0.f, 0.f};

    for (int c = 0; c < 4; ++c) {
        int t0 = c * 256;
        // ---- scores for this wave's 32 keys: D[q][key = w*32 + kt*16 + lm]
        f32x4 sacc[2];
        sacc[0] = f32x4{0.f, 0.f, 0.f, 0.f};
        sacc[1] = f32x4{0.f, 0.f, 0.f, 0.f};
        #pragma unroll
        for (int ks = 0; ks < 4; ++ks) {
            #pragma unroll
            for (int kt = 0; kt < 2; ++kt) {
                bf16x8 bfr = *(const bf16x8*)(kin + (size_t)(b * T_LEN + t0 + w * 32 + kt * 16 + lm) * KQ + ks * 32 + lg * 8);
                sacc[kt] = __builtin_amdgcn_mfma_f32_16x16x32_bf16(af[ks], bfr, sacc[kt], 0, 0, 0);
            }
        }
        // ---- per-wave row max -> LDS
        #pragma unroll
        for (int r = 0; r < 4; ++r) {
            float cm = fmaxf(sacc[0][r], sacc[1][r]);
            #pragma unroll
            for (int o = 8; o >= 1; o >>= 1) cm = fmaxf(cm, __shfl_xor(cm, o));
            if (lm == 0) redm[w][4 * lg + r] = cm;
        }
        __syncthreads();   // barrier 1: redm complete (and prev chunk's P_lds reads done)
        float fs[4];
        #pragma unroll
        for (int r = 0; r < 4; ++r) {
            int q = 4 * lg + r;
            float cm = redm[0][q];
            #pragma unroll
            for (int ww = 1; ww < 8; ++ww) cm = fmaxf(cm, redm[ww][q]);
            float nm = fmaxf(m_[r], cm * scale);
            fs[r] = __expf(m_[r] - nm);
            m_[r] = nm;
            float sum = 0.f;
            #pragma unroll
            for (int kt = 0; kt < 2; ++kt) {
                float p = __expf(sacc[kt][r] * scale - nm);
                sum += p;
                int key = w * 32 + kt * 16 + lm;
                P_lds[(q * 256 + key) ^ ((q & 7) << 3)] = __float2bfloat16(p);
            }
            #pragma unroll
            for (int o = 8; o >= 1; o >>= 1) sum += __shfl_xor(sum, o);
            if (lm == 0) reds[w][q] = sum;
            oacc[r] *= fs[r];
        }
        __syncthreads();   // barrier 2: P_lds + reds complete
        #pragma unroll
        for (int r = 0; r < 4; ++r) {
            int q = 4 * lg + r;
            float csum = reds[0][q];
            #pragma unroll
            for (int ww = 1; ww < 8; ++ww) csum += reds[ww][q];
            l_[r] = l_[r] * fs[r] + csum;
        }
        // ---- PV accumulate over all 256 chunk keys; wave owns v = w*16 + lm
        #pragma unroll
        for (int ks2 = 0; ks2 < 8; ++ks2) {
            bf16x8 pa = *(bf16x8*)&P_lds[(lm * 256 + ks2 * 32 + 8 * lg) ^ ((lm & 7) << 3)];
            bf16x8 xb = *(const bf16x8*)(xT + (size_t)(b * LD + w * 16 + lm) * T_LEN + t0 + ks2 * 32 + lg * 8);
            oacc = __builtin_amdgcn_mfma_f32_16x16x32_bf16(pa, xb, oacc, 0, 0, 0);
        }
    }

    // ---- normalize and store att bf16: att[b][q0+q][h*128 + w*16 + lm]
    #pragma unroll
    for (int r = 0; r < 4; ++r) {
        int q = 4 * lg + r;
        att[((size_t)(b * NREF + q0 + q)) * HLD + h * LD + w * 16 + lm] =
            __float2bfloat16(oacc[r] / l_[r]);
    }
}

// Output projection via MFMA: out[q][j] = att[q][:] @ WoT[j][:] + bo[j].
// grid (8 qt, 4 b, 4 js), block 64 (1 wave); wave owns 32 j cols.
__global__ __launch_bounds__(64) void proj_kernel(const __hip_bfloat16* __restrict__ att,
                                                  const __hip_bfloat16* __restrict__ WoT,
                                                  const float* __restrict__ bo,
                                                  float* __restrict__ out) {
    int lane = threadIdx.x;
    int lm = lane & 15, lg = lane >> 4;
    int q0 = blockIdx.x * 16, b = blockIdx.y, js = blockIdx.z;

    f32x4 cacc[2];
    cacc[0] = f32x4{0.f, 0.f, 0.f, 0.f};
    cacc[1] = f32x4{0.f, 0.f, 0.f, 0.f};
    #pragma unroll
    for (int ks = 0; ks < 16; ++ks) {
        bf16x8 aa = *(const bf16x8*)(att + (size_t)(b * NREF + q0 + lm) * HLD + ks * 32 + lg * 8);
        #pragma unroll
        for (int nt = 0; nt < 2; ++nt) {
            int j = js * 32 + nt * 16 + lm;
            bf16x8 wb = *(const bf16x8*)(WoT + (size_t)j * HLD + ks * 32 + lg * 8);
            cacc[nt] = __builtin_amdgcn_mfma_f32_16x16x32_bf16(aa, wb, cacc[nt], 0, 0, 0);
        }
    }
    #pragma unroll
    for (int nt = 0; nt < 2; ++nt) {
        int j = js * 32 + nt * 16 + lm;
        float bb = bo[j];
        #pragma unroll
        for (int r = 0; r < 4; ++r) {
            int q = q0 + 4 * lg + r;
            out[((size_t)b * NREF + q) * LD + j] = cacc[nt][r] + bb;
        }
    }
}

extern "C" void kernel_launch(void* const* d_in, const int* in_sizes, int n_in,
                              void* d_out, int out_size, void* d_ws, size_t ws_size,
                              hipStream_t stream) {
    const float* ts   = (const float*)d_in[0];
    const int*   ys0  = (const int*)d_in[1];
    const int*   ys1  = (const int*)d_in[2];
    const float* x    = (const float*)d_in[3];
    const float* emb0 = (const float*)d_in[4];
    const float* emb1 = (const float*)d_in[5];
    const float* Wq   = (const float*)d_in[6];
    const float* bq   = (const float*)d_in[7];
    const float* Wk   = (const float*)d_in[8];
    // d_in[9] = bk: cancels exactly in softmax (constant per (h,q) row) — unused
    const float* Wo   = (const float*)d_in[10];
    const float* bo   = (const float*)d_in[11];
    float* out = (float*)d_out;

    __hip_bfloat16* bfws = (__hip_bfloat16*)d_ws;
    __hip_bfloat16* A   = bfws;                 // 4*128*128      = 65536
    __hip_bfloat16* kin = A + 65536;            // 4096*128       = 524288
    __hip_bfloat16* xT  = kin + 524288;         // 4*128*1024     = 524288
    __hip_bfloat16* WoT = xT + 524288;          // 128*512        = 65536
    __hip_bfloat16* att = WoT + 65536;          // 4*128*512      = 262144
    // total 1,441,792 bf16 = 2.75 MB

    hipLaunchKernelGGL(pack_kernel, dim3(144), dim3(256), 0, stream,
                       ts, ys0, ys1, x, emb0, emb1, Wq, bq, Wk, Wo, A, kin, xT, WoT);
    hipLaunchKernelGGL(attn_kernel, dim3(8, 4, 4), dim3(512), 0, stream, A, kin, xT, att);
    hipLaunchKernelGGL(proj_kernel, dim3(8, 4, 4), dim3(64), 0, stream, att, WoT, bo, out);
}

// Round 7
// 36.532 us; speedup vs baseline: 2.9619x; 1.4168x over previous
//
#include <hip/hip_runtime.h>
#include <hip/hip_bf16.h>

#define N_B   4
#define T_LEN 1024
#define NREF  128
#define H     4
#define KQ    128
#define LD    128
#define HKQ   512
#define HLD   512

typedef __attribute__((ext_vector_type(8))) short bf16x8;   // 8 bf16 = 4 VGPRs
typedef __attribute__((ext_vector_type(4))) float f32x4;

union V8 { __hip_bfloat16 h[8]; bf16x8 v; };
union V4 { __hip_bfloat16 h[4]; ushort4 u; };

__device__ __forceinline__ void sincos_pair(float t, int i, float* s, float* c) {
    // freq i in [0,32): angle = 48*t*exp(-2i*ln(10)/64)
    float div = __expf(-(float)(2 * i) * (2.302585093f / 64.0f));
    __sincosf(48.0f * t * div, s, c);
}

// pack_kernel: job-dispatched producer kernel.
//  jobs 0..7    : A-tensor  (h = j>>1, q-half = j&1): hq = qin@Wq_h + bq (MFMA),
//                 then A_h = hq @ Wk_h^T (MFMA, Wk_h staged in LDS)
//  jobs 8..71   : k_in build (64 rows each) bf16 [4096][128]
//  jobs 72..135 : xT transpose x[b,t,v] f32 -> xT[b,v,t] bf16
//  jobs 136..143: WoT transpose Wo[512][128] f32 -> WoT[128][512] bf16 (64 i-rows each)
//  jobs 144..147: out init: out[b][q][j] = bo[j]
__global__ __launch_bounds__(256) void pack_kernel(
    const float* __restrict__ ts, const int* __restrict__ ys0, const int* __restrict__ ys1,
    const float* __restrict__ x,
    const float* __restrict__ emb0, const float* __restrict__ emb1,
    const float* __restrict__ Wq, const float* __restrict__ bq,
    const float* __restrict__ Wk, const float* __restrict__ Wo,
    const float* __restrict__ bo,
    __hip_bfloat16* __restrict__ A, __hip_bfloat16* __restrict__ kin,
    __hip_bfloat16* __restrict__ xT, __hip_bfloat16* __restrict__ WoT,
    float* __restrict__ out)
{
    __shared__ __align__(16) unsigned char smem[49152];
    int job = blockIdx.x;
    int tid = threadIdx.x;

    if (job < 8) {
        // ---------------- A job ----------------
        __hip_bfloat16* buf0 = (__hip_bfloat16*)smem;            // 64*128 bf16 = 16 KB (qin -> hq)
        __hip_bfloat16* wlds = (__hip_bfloat16*)(smem + 16384);  // 128*128 bf16 = 32 KB (WqT, then Wk_h)
        int h = job >> 1, qbase = (job & 1) * 64;

        // build qin (64 q rows x 128) bf16, XOR-swizzled rows
        for (int u = 0; u < 4; ++u) {
            int slot = u * 256 + tid;      // 0..1023
            int q = slot >> 4;             // local row 0..63
            int c0 = (slot & 15) * 8;
            V8 v;
            if (c0 < 64) {
                float t = (float)(qbase + q) / 127.0f;   // linspace(0,1,128)
                #pragma unroll
                for (int jj = 0; jj < 8; jj += 2) {
                    float s, c;
                    sincos_pair(t, (c0 + jj) >> 1, &s, &c);
                    v.h[jj] = __float2bfloat16(s);
                    v.h[jj + 1] = __float2bfloat16(c);
                }
            } else if (c0 < 96) {
                #pragma unroll
                for (int jj = 0; jj < 8; ++jj) v.h[jj] = __float2bfloat16(emb0[100 * 32 + (c0 - 64) + jj]);
            } else {
                #pragma unroll
                for (int jj = 0; jj < 8; ++jj) v.h[jj] = __float2bfloat16(emb1[50 * 32 + (c0 - 96) + jj]);
            }
            int idx = (q * 128 + c0) ^ ((q & 7) << 3);
            *(bf16x8*)&buf0[idx] = v.v;
        }
        // build WqT[d][i] bf16, swizzled (transpose of Wq_h); coalesced row reads
        for (int u = 0; u < 16; ++u) {
            int s = u * 256 + tid;         // 0..4095
            int i = s >> 5;                // 0..127
            int d0 = (s & 31) * 4;
            float4 w = *(const float4*)&Wq[(size_t)i * HKQ + h * KQ + d0];
            float wv[4] = {w.x, w.y, w.z, w.w};
            #pragma unroll
            for (int jj = 0; jj < 4; ++jj) {
                int d = d0 + jj;
                wlds[(d * 128 + i) ^ ((d & 7) << 3)] = __float2bfloat16(wv[jj]);
            }
        }
        __syncthreads();

        int wave = tid >> 6, lane = tid & 63, lm = lane & 15, lg = lane >> 4;
        // stage 1: hq[64q x 128d] = qin @ WqT + bq; wave owns 16 q rows
        f32x4 acc[8];
        #pragma unroll
        for (int dt = 0; dt < 8; ++dt) acc[dt] = f32x4{0.f, 0.f, 0.f, 0.f};
        #pragma unroll
        for (int ks = 0; ks < 4; ++ks) {
            int q = wave * 16 + lm;
            bf16x8 af = *(bf16x8*)&buf0[(q * 128 + ks * 32 + 8 * lg) ^ ((q & 7) << 3)];
            #pragma unroll
            for (int dt = 0; dt < 8; ++dt) {
                int d = dt * 16 + lm;
                bf16x8 bfr = *(bf16x8*)&wlds[(d * 128 + ks * 32 + 8 * lg) ^ ((d & 7) << 3)];
                acc[dt] = __builtin_amdgcn_mfma_f32_16x16x32_bf16(af, bfr, acc[dt], 0, 0, 0);
            }
        }
        __syncthreads();   // qin + WqT fully consumed
        // hq (+bias) -> buf0, swizzled
        #pragma unroll
        for (int dt = 0; dt < 8; ++dt) {
            int d = dt * 16 + lm;
            float bb = bq[h * KQ + d];
            #pragma unroll
            for (int r = 0; r < 4; ++r) {
                int q = wave * 16 + 4 * lg + r;
                buf0[(q * 128 + d) ^ ((q & 7) << 3)] = __float2bfloat16(acc[dt][r] + bb);
            }
        }
        // stage Wk_h rows (row-major, swizzled) into wlds; coalesced reads
        for (int u = 0; u < 16; ++u) {
            int s = u * 256 + tid;         // 0..4095
            int i = s >> 5;                // 0..127
            int d0 = (s & 31) * 4;
            float4 w = *(const float4*)&Wk[(size_t)i * HKQ + h * KQ + d0];
            V4 bv;
            bv.h[0] = __float2bfloat16(w.x); bv.h[1] = __float2bfloat16(w.y);
            bv.h[2] = __float2bfloat16(w.z); bv.h[3] = __float2bfloat16(w.w);
            *(ushort4*)&wlds[(i * 128 + d0) ^ ((i & 7) << 3)] = bv.u;
        }
        __syncthreads();
        // stage 2: A[64q x 128i] = hq @ Wk_h^T (contract d); B rows from LDS
        f32x4 acc2[8];
        #pragma unroll
        for (int it = 0; it < 8; ++it) acc2[it] = f32x4{0.f, 0.f, 0.f, 0.f};
        #pragma unroll
        for (int ks = 0; ks < 4; ++ks) {
            int q = wave * 16 + lm;
            bf16x8 af = *(bf16x8*)&buf0[(q * 128 + ks * 32 + 8 * lg) ^ ((q & 7) << 3)];
            #pragma unroll
            for (int it = 0; it < 8; ++it) {
                int i2 = it * 16 + lm;
                bf16x8 bv = *(bf16x8*)&wlds[(i2 * 128 + ks * 32 + 8 * lg) ^ ((i2 & 7) << 3)];
                acc2[it] = __builtin_amdgcn_mfma_f32_16x16x32_bf16(af, bv, acc2[it], 0, 0, 0);
            }
        }
        // store A: [h][q][i] bf16 (plain row-major)
        #pragma unroll
        for (int it = 0; it < 8; ++it) {
            int i2 = it * 16 + lm;
            #pragma unroll
            for (int r = 0; r < 4; ++r) {
                int q = qbase + wave * 16 + 4 * lg + r;
                A[((size_t)h * NREF + q) * KQ + i2] = __float2bfloat16(acc2[it][r]);
            }
        }
    } else if (job < 72) {
        // ---------------- k_in job ----------------
        int row0 = (job - 8) * 64;
        for (int u = 0; u < 4; ++u) {
            int slot = u * 256 + tid;     // 0..1023
            int r = slot >> 4;            // 0..63
            int c0 = (slot & 15) * 8;
            int bt = row0 + r;
            V8 v;
            if (c0 < 64) {
                float t = ts[bt];
                #pragma unroll
                for (int jj = 0; jj < 8; jj += 2) {
                    float s, c;
                    sincos_pair(t, (c0 + jj) >> 1, &s, &c);
                    v.h[jj] = __float2bfloat16(s);
                    v.h[jj + 1] = __float2bfloat16(c);
                }
            } else if (c0 < 96) {
                int y = ys0[bt];
                #pragma unroll
                for (int jj = 0; jj < 8; ++jj) v.h[jj] = __float2bfloat16(emb0[y * 32 + (c0 - 64) + jj]);
            } else {
                int y = ys1[bt];
                #pragma unroll
                for (int jj = 0; jj < 8; ++jj) v.h[jj] = __float2bfloat16(emb1[y * 32 + (c0 - 96) + jj]);
            }
            *(bf16x8*)&kin[(size_t)bt * KQ + c0] = v.v;
        }
    } else if (job < 136) {
        // ---------------- xT job ----------------
        __hip_bfloat16 (*tile)[136] = (__hip_bfloat16(*)[136])smem;   // 64*136*2 = 17.4 KB
        int jb = job - 72;
        int b = jb >> 4, t0 = (jb & 15) * 64;
        for (int e = tid; e < 64 * 32; e += 256) {
            int tt = e >> 5, v4 = e & 31;
            float4 xv = *(const float4*)&x[((size_t)(b * T_LEN + t0 + tt)) * LD + v4 * 4];
            tile[tt][v4 * 4 + 0] = __float2bfloat16(xv.x);
            tile[tt][v4 * 4 + 1] = __float2bfloat16(xv.y);
            tile[tt][v4 * 4 + 2] = __float2bfloat16(xv.z);
            tile[tt][v4 * 4 + 3] = __float2bfloat16(xv.w);
        }
        __syncthreads();
        int v = tid >> 1, th = (tid & 1) * 32;
        for (int i = 0; i < 32; i += 4) {
            ushort4 u;
            u.x = *(unsigned short*)&tile[th + i + 0][v];
            u.y = *(unsigned short*)&tile[th + i + 1][v];
            u.z = *(unsigned short*)&tile[th + i + 2][v];
            u.w = *(unsigned short*)&tile[th + i + 3][v];
            *(ushort4*)&xT[((size_t)b * LD + v) * T_LEN + t0 + th + i] = u;
        }
    } else if (job < 144) {
        // ---------------- WoT job: Wo[i][j] f32 -> WoT[j][i] bf16, 64-row i slab ----------------
        __hip_bfloat16 (*tile)[130] = (__hip_bfloat16(*)[130])smem;   // 64*130*2 = 16.6 KB
        int i0 = (job - 136) * 64;
        for (int u = 0; u < 32; ++u) {
            int e = u * 256 + tid;            // 0..8191
            int il = e >> 7, j = e & 127;
            tile[il][j] = __float2bfloat16(Wo[(size_t)(i0 + il) * LD + j]);
        }
        __syncthreads();
        for (int u = 0; u < 32; ++u) {
            int s = u * 256 + tid;            // 0..8191
            int j = s >> 6, il = s & 63;
            WoT[(size_t)j * HLD + i0 + il] = tile[il][j];
        }
    } else {
        // ---------------- out init: out[b][q][j] = bo[j] ----------------
        int b = job - 144;
        for (int e = tid; e < NREF * LD; e += 256)
            out[(size_t)b * NREF * LD + e] = bo[e & 127];
    }
}

// Fused attention + partial output projection for one (16q, h, b).
// 8 waves: wave w scores keys [w*128,(w+1)*128) (32 MFMA), ONE cross-wave max+sum
// (exact two-pass softmax, no online rescale), exp -> P_lds bf16 (swizzled),
// PV over all 1024 keys for v = w*16+lm (32 MFMA), normalize -> att_lds,
// then partial proj att_h @ Wo_h (4 MFMA) atomicAdd'ed into out (out pre-init = bo).
// grid (8 qt, 4 h, 4 b), block 512.
__global__ __launch_bounds__(512) void attn_proj(const __hip_bfloat16* __restrict__ A,
                                                 const __hip_bfloat16* __restrict__ kin,
                                                 const __hip_bfloat16* __restrict__ xT,
                                                 const __hip_bfloat16* __restrict__ WoT,
                                                 float* __restrict__ out) {
    __shared__ __hip_bfloat16 P_lds[16 * 1024];   // 32 KB, XOR-swizzled rows
    __shared__ __hip_bfloat16 att_lds[16 * 128];  // 4 KB, XOR-swizzled rows
    __shared__ float redm[8][16], reds[8][16];

    int tid = threadIdx.x;
    int w = tid >> 6, lane = tid & 63;
    int lm = lane & 15, lg = lane >> 4;
    int q0 = blockIdx.x * 16, h = blockIdx.y, b = blockIdx.z;
    const float scale = 0.08838834764831845f;  // 1/sqrt(128)

    // A-frags for the 16 q rows
    bf16x8 af[4];
    #pragma unroll
    for (int ks = 0; ks < 4; ++ks)
        af[ks] = *(const bf16x8*)(A + ((size_t)h * NREF + q0 + lm) * KQ + ks * 32 + lg * 8);

    // ---- scores for this wave's 128 keys: D[q=4lg+r][key = w*128 + kt*16 + lm]
    f32x4 sacc[8];
    #pragma unroll
    for (int kt = 0; kt < 8; ++kt) sacc[kt] = f32x4{0.f, 0.f, 0.f, 0.f};
    #pragma unroll
    for (int ks = 0; ks < 4; ++ks) {
        #pragma unroll
        for (int kt = 0; kt < 8; ++kt) {
            bf16x8 bfr = *(const bf16x8*)(kin + (size_t)(b * T_LEN + w * 128 + kt * 16 + lm) * KQ + ks * 32 + lg * 8);
            sacc[kt] = __builtin_amdgcn_mfma_f32_16x16x32_bf16(af[ks], bfr, sacc[kt], 0, 0, 0);
        }
    }
    // ---- per-wave row max -> LDS
    #pragma unroll
    for (int r = 0; r < 4; ++r) {
        float cm = sacc[0][r];
        #pragma unroll
        for (int kt = 1; kt < 8; ++kt) cm = fmaxf(cm, sacc[kt][r]);
        #pragma unroll
        for (int o = 8; o >= 1; o >>= 1) cm = fmaxf(cm, __shfl_xor(cm, o));
        if (lm == 0) redm[w][4 * lg + r] = cm;
    }
    __syncthreads();   // barrier 1: redm complete
    // ---- global row max, exp -> P_lds, per-wave sums
    #pragma unroll
    for (int r = 0; r < 4; ++r) {
        int q = 4 * lg + r;
        float cm = redm[0][q];
        #pragma unroll
        for (int ww = 1; ww < 8; ++ww) cm = fmaxf(cm, redm[ww][q]);
        float fm = cm * scale;
        float sum = 0.f;
        #pragma unroll
        for (int kt = 0; kt < 8; ++kt) {
            float p = __expf(sacc[kt][r] * scale - fm);
            sum += p;
            int key = w * 128 + kt * 16 + lm;
            P_lds[(q * 1024 + key) ^ ((q & 7) << 3)] = __float2bfloat16(p);
        }
        #pragma unroll
        for (int o = 8; o >= 1; o >>= 1) sum += __shfl_xor(sum, o);
        if (lm == 0) reds[w][q] = sum;
    }
    __syncthreads();   // barrier 2: P_lds + reds complete
    float l_[4];
    #pragma unroll
    for (int r = 0; r < 4; ++r) {
        int q = 4 * lg + r;
        float csum = reds[0][q];
        #pragma unroll
        for (int ww = 1; ww < 8; ++ww) csum += reds[ww][q];
        l_[r] = csum;
    }
    // ---- PV over all 1024 keys; wave owns v = w*16 + lm
    f32x4 oacc = f32x4{0.f, 0.f, 0.f, 0.f};
    const __hip_bfloat16* xb0 = xT + (size_t)(b * LD + w * 16 + lm) * T_LEN;
    #pragma unroll
    for (int ks2 = 0; ks2 < 32; ++ks2) {
        bf16x8 pa = *(bf16x8*)&P_lds[(lm * 1024 + ks2 * 32 + 8 * lg) ^ ((lm & 7) << 3)];
        bf16x8 xb = *(const bf16x8*)(xb0 + ks2 * 32 + lg * 8);
        oacc = __builtin_amdgcn_mfma_f32_16x16x32_bf16(pa, xb, oacc, 0, 0, 0);
    }
    // ---- normalize -> att_lds (bf16, swizzled): rows q, col v = w*16+lm
    #pragma unroll
    for (int r = 0; r < 4; ++r) {
        int q = 4 * lg + r;
        att_lds[(q * 128 + w * 16 + lm) ^ ((q & 7) << 3)] = __float2bfloat16(oacc[r] / l_[r]);
    }
    __syncthreads();   // barrier 3: att_lds complete
    // ---- partial projection: wave owns j-tile [w*16, w*16+16)
    f32x4 cacc = f32x4{0.f, 0.f, 0.f, 0.f};
    #pragma unroll
    for (int ks = 0; ks < 4; ++ks) {
        bf16x8 aa = *(bf16x8*)&att_lds[(lm * 128 + ks * 32 + 8 * lg) ^ ((lm & 7) << 3)];
        bf16x8 wb = *(const bf16x8*)(WoT + (size_t)(w * 16 + lm) * HLD + h * LD + ks * 32 + lg * 8);
        cacc = __builtin_amdgcn_mfma_f32_16x16x32_bf16(aa, wb, cacc, 0, 0, 0);
    }
    #pragma unroll
    for (int r = 0; r < 4; ++r) {
        int q = q0 + 4 * lg + r;
        atomicAdd(&out[((size_t)b * NREF + q) * LD + w * 16 + lm], cacc[r]);
    }
}

extern "C" void kernel_launch(void* const* d_in, const int* in_sizes, int n_in,
                              void* d_out, int out_size, void* d_ws, size_t ws_size,
                              hipStream_t stream) {
    const float* ts   = (const float*)d_in[0];
    const int*   ys0  = (const int*)d_in[1];
    const int*   ys1  = (const int*)d_in[2];
    const float* x    = (const float*)d_in[3];
    const float* emb0 = (const float*)d_in[4];
    const float* emb1 = (const float*)d_in[5];
    const float* Wq   = (const float*)d_in[6];
    const float* bq   = (const float*)d_in[7];
    const float* Wk   = (const float*)d_in[8];
    // d_in[9] = bk: cancels exactly in softmax (constant per (h,q) row) — unused
    const float* Wo   = (const float*)d_in[10];
    const float* bo   = (const float*)d_in[11];
    float* out = (float*)d_out;

    __hip_bfloat16* bfws = (__hip_bfloat16*)d_ws;
    __hip_bfloat16* A   = bfws;                 // 4*128*128      = 65536
    __hip_bfloat16* kin = A + 65536;            // 4096*128       = 524288
    __hip_bfloat16* xT  = kin + 524288;         // 4*128*1024     = 524288
    __hip_bfloat16* WoT = xT + 524288;          // 128*512        = 65536
    // total 1,179,648 bf16 = 2.25 MB

    hipLaunchKernelGGL(pack_kernel, dim3(148), dim3(256), 0, stream,
                       ts, ys0, ys1, x, emb0, emb1, Wq, bq, Wk, Wo, bo, A, kin, xT, WoT, out);
    hipLaunchKernelGGL(attn_proj, dim3(8, 4, 4), dim3(512), 0, stream, A, kin, xT, WoT, out);
}